// Round 19
// baseline (389.220 us; speedup 1.0000x reference)
//
#include <hip/hip_runtime.h>
#include <hip/hip_bf16.h>

#define DM   1024
#define DFF  4096
#define NH   16
#define HD   64
#define SEQ  2048
#define BATCH 4
#define NTOK (BATCH*SEQ)

typedef float  f32x4  __attribute__((ext_vector_type(4)));
typedef short  bf16x8 __attribute__((ext_vector_type(8)));

#define SBAR() asm volatile("s_barrier" ::: "memory")
#define S_VMCNT(N) asm volatile("s_waitcnt vmcnt(" #N ")" ::: "memory")

__device__ __forceinline__ unsigned short f2bf(float f) {
    unsigned int x = __builtin_bit_cast(unsigned int, f);
    x += 0x7fff + ((x >> 16) & 1);          // RNE; inputs finite
    return (unsigned short)(x >> 16);
}
__device__ __forceinline__ float bf2f(unsigned short u) {
    unsigned int x = (unsigned int)u << 16;
    return __builtin_bit_cast(float, x);
}

__device__ __forceinline__ float fexp2(float x) {     // 2^x, single v_exp_f32
    float r; asm("v_exp_f32 %0, %1" : "=v"(r) : "v"(x)); return r;
}
__device__ __forceinline__ float frcp(float x) {
    float r; asm("v_rcp_f32 %0, %1" : "=v"(r) : "v"(x)); return r;
}

__device__ __forceinline__ void gload_lds16(const void* g, void* l) {
    // dest is wave-uniform base; HW writes base + lane*16
    __builtin_amdgcn_global_load_lds(
        (const __attribute__((address_space(1))) unsigned int*)g,
        (__attribute__((address_space(3))) unsigned int*)l,
        16, 0, 0);
}

// XOR swizzle for [R][64] bf16 tiles: element index within row
__device__ __forceinline__ int swz(int row, int elem) { return elem ^ ((row & 7) << 3); }

// ---------------- fused prep: weight transposes (blocks 0..12287) + rmsnorm1 (12288..) ----
__global__ __launch_bounds__(256)
void prep_all(const float* __restrict__ qkv_w, const float* __restrict__ out_w,
              const float* __restrict__ ff1_w, const float* __restrict__ ff2_w,
              unsigned short* __restrict__ qkv_wt, unsigned short* __restrict__ out_wt,
              unsigned short* __restrict__ ff1_wt, unsigned short* __restrict__ ff2_wt,
              const float* __restrict__ src, const float* __restrict__ n1_w,
              unsigned short* __restrict__ xb)
{
    __shared__ float tile[32][33];
    int b = blockIdx.x;
    if (b < 12288) {
        const float* W; unsigned short* Wt; int K, N, bx, by;
        if (b < 3072)      { W = qkv_w; Wt = qkv_wt; K = 1024; N = 3072; bx = b % 96;  by = b / 96;  }
        else if (b < 4096) { int i = b - 3072; W = out_w; Wt = out_wt; K = 1024; N = 1024; bx = i % 32;  by = i / 32; }
        else if (b < 8192) { int i = b - 4096; W = ff1_w; Wt = ff1_wt; K = 1024; N = 4096; bx = i % 128; by = i / 128; }
        else               { int i = b - 8192; W = ff2_w; Wt = ff2_wt; K = 4096; N = 1024; bx = i % 32;  by = i / 32; }
        int n0 = bx * 32, k0 = by * 32;
        int tx = threadIdx.x & 31, ty = threadIdx.x >> 5;   // 32 x 8
        #pragma unroll
        for (int i = 0; i < 4; ++i)
            tile[ty + i*8][tx] = W[(size_t)(k0 + ty + i*8) * N + n0 + tx];
        __syncthreads();
        #pragma unroll
        for (int i = 0; i < 4; ++i)
            Wt[(size_t)(n0 + ty + i*8) * K + k0 + tx] = f2bf(tile[tx][ty + i*8]);
    } else {
        int row = b - 12288, t = threadIdx.x;
        float4 v = ((const float4*)(src + (size_t)row * DM))[t];
        float ss = v.x*v.x + v.y*v.y + v.z*v.z + v.w*v.w;
        #pragma unroll
        for (int m = 1; m < 64; m <<= 1) ss += __shfl_xor(ss, m);
        if ((t & 63) == 0) tile[0][t >> 6] = ss;
        __syncthreads();
        float tot = tile[0][0] + tile[0][1] + tile[0][2] + tile[0][3];
        float rms = sqrtf(tot) * (1.f / 32.f);
        float inv = 1.f / (rms + 1e-8f);
        float4 wv = ((const float4*)n1_w)[t];
        unsigned int lo = (unsigned int)f2bf(v.x*inv*wv.x) | ((unsigned int)f2bf(v.y*inv*wv.y) << 16);
        unsigned int hi = (unsigned int)f2bf(v.z*inv*wv.z) | ((unsigned int)f2bf(v.w*inv*wv.w) << 16);
        uint2 pk; pk.x = lo; pk.y = hi;
        *(uint2*)(xb + (size_t)row * DM + t * 4) = pk;
    }
}

// ---------------- RMSNorm: bf16 in -> bf16 out (norm2) ----------------
__global__ __launch_bounds__(256)
void rmsnorm_kernel(const unsigned short* __restrict__ inp, const float* __restrict__ w,
                    unsigned short* __restrict__ out)
{
    __shared__ float red[4];
    int row = blockIdx.x, t = threadIdx.x;
    ushort4 u = ((const ushort4*)(inp + (size_t)row * DM))[t];
    float x0 = bf2f(u.x), x1 = bf2f(u.y), x2 = bf2f(u.z), x3 = bf2f(u.w);
    float ss = x0*x0 + x1*x1 + x2*x2 + x3*x3;
    #pragma unroll
    for (int m = 1; m < 64; m <<= 1) ss += __shfl_xor(ss, m);
    if ((t & 63) == 0) red[t >> 6] = ss;
    __syncthreads();
    float tot = red[0] + red[1] + red[2] + red[3];
    float rms = sqrtf(tot) * (1.f / 32.f);
    float inv = 1.f / (rms + 1e-8f);
    float4 wv = ((const float4*)w)[t];
    unsigned int lo = (unsigned int)f2bf(x0*inv*wv.x) | ((unsigned int)f2bf(x1*inv*wv.y) << 16);
    unsigned int hi = (unsigned int)f2bf(x2*inv*wv.z) | ((unsigned int)f2bf(x3*inv*wv.w) << 16);
    uint2 pk; pk.x = lo; pk.y = hi;
    *(uint2*)(out + (size_t)row * DM + t * 4) = pk;
}

// ---------------- 256xNB 8-phase GEMM, BK=64 as 2 K-halves, counted vmcnt (R14) ----------
// MODE 0: qkv scatter -> q (prescaled 0.125*log2e), k, v transposed (V packed 8B stores)
// MODE 2: out = gelu_tanh(acc + bias) (bf16)
// MODE 4: out = f2bf(acc + bias + fp32resid) (bf16 out) [out-proj]
template<int MODE, int NB>
__global__ __launch_bounds__(512, 2)
void gemm_tpl(const unsigned short* __restrict__ A,
              const unsigned short* __restrict__ Bt,
              const float* __restrict__ bias,
              int N, int K, int nx,
              const float* __restrict__ residf,
              float* __restrict__ outf,
              unsigned short* __restrict__ outb,
              unsigned short* __restrict__ q,
              unsigned short* __restrict__ kk,
              unsigned short* __restrict__ vt)
{
    constexpr int NJ = NB / 64;                        // B frags per wave
    constexpr int WN = NB / 4;                         // wave N extent
    __shared__ __align__(16) unsigned short Atile[2][2][256 * 32];
    __shared__ __align__(16) unsigned short Btile[2][2][NB * 32];
    const int tid = threadIdx.x, w = tid >> 6, l = tid & 63;
    const int lr = l & 15, lh = l >> 4;
    const int wm = w >> 2, wn = w & 3;                 // 2M x 4N
    const int nwg = gridDim.x, cpx = nwg >> 3;
    const int sid = (blockIdx.x & 7) * cpx + (blockIdx.x >> 3);
    const int by = sid / nx, bx = sid - by * nx;
    const int m0 = by * 256, n0 = bx * NB;
    const int nkt = K >> 6;
    // staging geometry: one gload covers 128 rows x 32 elems (8 waves x 16 rows)
    const int srow = w * 16 + (l >> 2);                // row within 128-row unit
    const int scol = (((l & 3) ^ (srow & 3)) << 3);    // pre-swizzled elem col

    auto stageA = [&](int kt, int ks, int half, int bi) {
        int r0 = half * 128;
        gload_lds16(A + (size_t)(m0 + r0 + srow) * K + kt * 64 + ks * 32 + scol,
                    &Atile[bi][ks][(r0 + w * 16) * 32]);
    };
    auto stageB = [&](int kt, int ks, int half, int bi) {
        int r0 = half * 128;
        gload_lds16(Bt + (size_t)(n0 + r0 + srow) * K + kt * 64 + ks * 32 + scol,
                    &Btile[bi][ks][(r0 + w * 16) * 32]);
    };

    f32x4 acc[8][NJ];
    #pragma unroll
    for (int a = 0; a < 8; ++a)
        #pragma unroll
        for (int j = 0; j < NJ; ++j) acc[a][j] = {0.f, 0.f, 0.f, 0.f};

    // prologue: tile 0, groups in wait-order [ks0][ks1]
    #pragma unroll
    for (int ks = 0; ks < 2; ++ks) {
        stageA(0, ks, 0, 0); stageA(0, ks, 1, 0);
        stageB(0, ks, 0, 0);
        if (NB == 256) stageB(0, ks, 1, 0);
    }

    int bi = 0;
    for (int t = 0; t < nkt; ++t) {
        #pragma unroll
        for (int ks = 0; ks < 2; ++ks) {
            // entry sync: this ks-half landed for all waves; one newer group may fly
            if (ks == 0 || t + 1 < nkt) {
                if constexpr (NB == 256) { S_VMCNT(4); } else { S_VMCNT(3); }
            } else {
                S_VMCNT(0);
            }
            SBAR();
            bf16x8 bB[NJ];
            #pragma unroll
            for (int j = 0; j < NJ; ++j) {
                int row = wn * WN + j * 16 + lr;
                bB[j] = *(const bf16x8*)&Btile[bi][ks][row * 32 + ((lh ^ (row & 3)) << 3)];
            }
            #pragma unroll
            for (int rho = 0; rho < 2; ++rho) {
                bf16x8 aA[4];
                #pragma unroll
                for (int i = 0; i < 4; ++i) {
                    int row = wm * 128 + rho * 64 + i * 16 + lr;
                    aA[i] = *(const bf16x8*)&Atile[bi][ks][row * 32 + ((lh ^ (row & 3)) << 3)];
                }
                // stage tile t+1: rho0 -> A-ks half, rho1 -> B-ks half
                if (t + 1 < nkt) {
                    if (rho == 0) { stageA(t + 1, ks, 0, bi ^ 1); stageA(t + 1, ks, 1, bi ^ 1); }
                    else          { stageB(t + 1, ks, 0, bi ^ 1);
                                    if (NB == 256) stageB(t + 1, ks, 1, bi ^ 1); }
                }
                SBAR();
                __builtin_amdgcn_s_setprio(1);
                #pragma unroll
                for (int i = 0; i < 4; ++i)
                    #pragma unroll
                    for (int j = 0; j < NJ; ++j)
                        acc[rho * 4 + i][j] = __builtin_amdgcn_mfma_f32_16x16x32_bf16(
                            aA[i], bB[j], acc[rho * 4 + i][j], 0, 0, 0);
                __builtin_amdgcn_s_setprio(0);
            }
        }
        bi ^= 1;
    }

    #pragma unroll
    for (int a = 0; a < 8; ++a) {
        const int rho = a >> 2, i = a & 3;
        #pragma unroll
        for (int j = 0; j < NJ; ++j) {
            const int col = n0 + wn * WN + j * 16 + lr;
            const int row0 = m0 + wm * 128 + rho * 64 + i * 16 + lh * 4;
            if (MODE == 0) {
                float v0 = acc[a][j][0] + bias[col];
                float v1 = acc[a][j][1] + bias[col];
                float v2 = acc[a][j][2] + bias[col];
                float v3 = acc[a][j][3] + bias[col];
                int wh = col >> 10, h = (col >> 6) & 15, d = col & 63;
                int b = row0 >> 11, s0 = row0 & 2047;
                size_t base = (size_t)(b * NH + h);
                if (wh == 0) {
                    q[(base * SEQ + s0    ) * HD + d] = f2bf(v0 * 0.18033688f);
                    q[(base * SEQ + s0 + 1) * HD + d] = f2bf(v1 * 0.18033688f);
                    q[(base * SEQ + s0 + 2) * HD + d] = f2bf(v2 * 0.18033688f);
                    q[(base * SEQ + s0 + 3) * HD + d] = f2bf(v3 * 0.18033688f);
                } else if (wh == 1) {
                    kk[(base * SEQ + s0    ) * HD + d] = f2bf(v0);
                    kk[(base * SEQ + s0 + 1) * HD + d] = f2bf(v1);
                    kk[(base * SEQ + s0 + 2) * HD + d] = f2bf(v2);
                    kk[(base * SEQ + s0 + 3) * HD + d] = f2bf(v3);
                } else {
                    // 4 consecutive s -> one 8B store into vt[d][s]
                    uint2 pk;
                    pk.x = (unsigned int)f2bf(v0) | ((unsigned int)f2bf(v1) << 16);
                    pk.y = (unsigned int)f2bf(v2) | ((unsigned int)f2bf(v3) << 16);
                    *(uint2*)&vt[(base * HD + d) * SEQ + s0] = pk;
                }
            } else {
                #pragma unroll
                for (int r = 0; r < 4; ++r) {
                    int row = row0 + r;
                    float v = acc[a][j][r] + bias[col];
                    if (MODE == 2) {
                        // tanh-form GELU: x*u/(u+1), u = 2^(2.3022079*(x+0.044715 x^3))
                        float x = v;
                        float t2 = fmaf(x * x * x, 0.044715f, x);
                        float av = fminf(t2 * 2.3022079f, 80.f);
                        float u = fexp2(av);
                        float g = x * u * frcp(u + 1.f);
                        outb[(size_t)row * N + col] = f2bf(g);
                    } else {
                        outb[(size_t)row * N + col] = f2bf(v + residf[(size_t)row * N + col]);
                    }
                }
            }
        }
    }
}

// ---------------- ff2: m97-replica 128x128 2-phase GEMM, 32KB LDS (high occupancy) ------
// R3-proven structure verbatim; fp32 out = acc + bias + bf16 resid; 1D XCD-chunked grid.
__global__ __launch_bounds__(256)
void gemm_ff2(const unsigned short* __restrict__ A,
              const unsigned short* __restrict__ Bt,
              const float* __restrict__ bias,
              int N, int K, int nx,
              const unsigned short* __restrict__ residb,
              float* __restrict__ outf)
{
    __shared__ __align__(16) unsigned short As[128 * 64];
    __shared__ __align__(16) unsigned short Bs[128 * 64];
    const int tid = threadIdx.x;
    const int w = tid >> 6, l = tid & 63;
    const int lr = l & 15, lh = l >> 4;
    const int nwg = gridDim.x, cpx = nwg >> 3;
    const int sid = (blockIdx.x & 7) * cpx + (blockIdx.x >> 3);
    const int by = sid / nx, bx = sid - by * nx;
    const int m0 = by * 128, n0 = bx * 128;
    const int wr = (w >> 1) * 64, wc = (w & 1) * 64;

    f32x4 acc[4][4];
    #pragma unroll
    for (int i = 0; i < 4; ++i)
        #pragma unroll
        for (int j = 0; j < 4; ++j) acc[i][j] = {0.f, 0.f, 0.f, 0.f};

    const int nkt = K >> 6;
    for (int kt = 0; kt < nkt; ++kt) {
        __syncthreads();
        #pragma unroll
        for (int c = 0; c < 4; ++c) {
            int rbase = w * 32 + c * 8;
            int row = rbase + (l >> 3);
            int col = (l & 7) * 8;
            gload_lds16(A  + (size_t)(m0 + row) * K + kt * 64 + col, &As[rbase * 64]);
            gload_lds16(Bt + (size_t)(n0 + row) * K + kt * 64 + col, &Bs[rbase * 64]);
        }
        __syncthreads();
        #pragma unroll
        for (int ks = 0; ks < 2; ++ks) {
            bf16x8 af[4], bfv[4];
            #pragma unroll
            for (int i = 0; i < 4; ++i)
                af[i] = *(const bf16x8*)&As[(wr + i*16 + lr) * 64 + ks*32 + lh*8];
            #pragma unroll
            for (int j = 0; j < 4; ++j)
                bfv[j] = *(const bf16x8*)&Bs[(wc + j*16 + lr) * 64 + ks*32 + lh*8];
            #pragma unroll
            for (int i = 0; i < 4; ++i)
                #pragma unroll
                for (int j = 0; j < 4; ++j)
                    acc[i][j] = __builtin_amdgcn_mfma_f32_16x16x32_bf16(af[i], bfv[j], acc[i][j], 0, 0, 0);
        }
    }

    #pragma unroll
    for (int i = 0; i < 4; ++i)
        #pragma unroll
        for (int j = 0; j < 4; ++j)
            #pragma unroll
            for (int r = 0; r < 4; ++r) {
                int row = m0 + wr + i*16 + lh*4 + r;
                int col = n0 + wc + j*16 + lr;
                float v = acc[i][j][r] + bias[col];
                outf[(size_t)row * N + col] = v + bf2f(residb[(size_t)row * N + col]);
            }
}

// ---------------- flash attention: 4 waves x 64 q-rows (256/block), KVBLK=64 ----------------
// NO max-tracking (norm-bounded scores); row-sums via ones-column MFMA.
// 512 blocks @ 64KB = exactly 2/CU, no tail.
__global__ __launch_bounds__(256, 2)
void attn_kernel(const unsigned short* __restrict__ q,
                 const unsigned short* __restrict__ k,
                 const unsigned short* __restrict__ vt,
                 unsigned short* __restrict__ ctx)
{
    __shared__ __align__(16) unsigned short Ks[2][64 * 64];    // 16 KB
    __shared__ __align__(16) unsigned short Vs[2][64 * 64];    // 16 KB [d][s]
    __shared__ __align__(16) unsigned short PQ[4][64 * 64];    // 32 KB: Q prologue, then P

    const int tid = threadIdx.x, w = tid >> 6, l = tid & 63;
    const int lr = l & 15, lh = l >> 4;

    // XCD-chunked: 512 blocks = 8 XCDs x 64; each XCD owns 8 heads
    const int sid = (blockIdx.x & 7) * 64 + (blockIdx.x >> 3);
    const int bh = sid >> 3, qt = sid & 7;
    const int b = bh >> 4, h = bh & 15;

    const int rloc = l >> 3;
    const int cswz = (((l & 7) ^ rloc) << 3);

    const unsigned short* kbase0 = k  + (size_t)bh * SEQ * HD;
    const unsigned short* vbase0 = vt + (size_t)bh * HD * SEQ;
    const int NT = SEQ / 64;

    auto stageK = [&](int t, int buf) {
        const unsigned short* kb = kbase0 + (size_t)t * 64 * HD;
        #pragma unroll
        for (int c = 0; c < 2; ++c) {
            int r0 = (w * 2 + c) * 8;
            gload_lds16(kb + (size_t)(r0 + rloc) * HD + cswz, &Ks[buf][r0 * 64]);
        }
    };
    auto stageV = [&](int t, int buf) {
        const unsigned short* vb = vbase0 + t * 64;
        #pragma unroll
        for (int c = 0; c < 2; ++c) {
            int d0 = w * 16 + c * 8;
            gload_lds16(vb + (size_t)(d0 + rloc) * SEQ + cswz, &Vs[buf][d0 * 64]);
        }
    };

    // prologue: wave stages its OWN 64 Q rows into PQ[w], then K/V tile 0
    unsigned short* Pw = &PQ[w][0];
    const unsigned short* qbase = q + ((size_t)bh * SEQ + qt * 256 + w * 64) * HD;
    #pragma unroll
    for (int c = 0; c < 8; ++c) {
        int r0 = c * 8;
        gload_lds16(qbase + (size_t)(r0 + rloc) * HD + cswz, &Pw[r0 * 64]);
    }
    stageK(0, 0);
    stageV(0, 0);
    S_VMCNT(4);                                      // own 8 Q loads done (K/V are 4 newest)
    bf16x8 aq[4][2];
    #pragma unroll
    for (int g = 0; g < 4; ++g) {
        int row = g * 16 + lr;
        aq[g][0] = *(const bf16x8*)&Pw[row * 64 + swz(row,      lh * 8)];
        aq[g][1] = *(const bf16x8*)&Pw[row * 64 + swz(row, 32 + lh * 8)];
    }
    __syncthreads();                                 // K/V tile 0 visible; PQ free for P

    bf16x8 vone;
    #pragma unroll
    for (int i = 0; i < 8; ++i) vone[i] = (short)0x3F80;   // bf16 1.0

    f32x4 lacc[4];
    f32x4 o[4][4];
    #pragma unroll
    for (int g = 0; g < 4; ++g) {
        lacc[g] = {0.f, 0.f, 0.f, 0.f};
        #pragma unroll
        for (int nf = 0; nf < 4; ++nf) o[g][nf] = {0.f, 0.f, 0.f, 0.f};
    }

    for (int t = 0; t < NT; ++t) {
        const int cur = t & 1;
        if (t + 1 < NT) { stageK(t + 1, cur ^ 1); stageV(t + 1, cur ^ 1); }

        const unsigned short* Kc = &Ks[cur][0];
        const unsigned short* Vc = &Vs[cur][0];

        // K frags read ONCE, reused across 4 q-groups
        bf16x8 kb[4][2];
        #pragma unroll
        for (int j = 0; j < 4; ++j) {
            int kr = j * 16 + lr;
            kb[j][0] = *(const bf16x8*)&Kc[kr * 64 + swz(kr,      lh * 8)];
            kb[j][1] = *(const bf16x8*)&Kc[kr * 64 + swz(kr, 32 + lh * 8)];
        }

        #pragma unroll
        for (int g = 0; g < 4; ++g) {
            // QK^T (log2-scaled scores; lane owns q = g*16+lr)
            f32x4 sc[4];
            __builtin_amdgcn_s_setprio(1);
            #pragma unroll
            for (int j = 0; j < 4; ++j) {
                f32x4 z = {0.f, 0.f, 0.f, 0.f};
                z = __builtin_amdgcn_mfma_f32_16x16x32_bf16(kb[j][0], aq[g][0], z, 0, 0, 0);
                z = __builtin_amdgcn_mfma_f32_16x16x32_bf16(kb[j][1], aq[g][1], z, 0, 0, 0);
                sc[j] = z;
            }
            __builtin_amdgcn_s_setprio(0);

            // P = 2^s (no max subtraction needed), pack bf16, b64 store to swizzled Pw
            int prow = g * 16 + lr;
            #pragma unroll
            for (int j = 0; j < 4; ++j) {
                float p0 = fexp2(sc[j][0]), p1 = fexp2(sc[j][1]);
                float p2 = fexp2(sc[j][2]), p3 = fexp2(sc[j][3]);
                unsigned int w0, w1;
                asm("v_cvt_pk_bf16_f32 %0, %1, %2" : "=v"(w0) : "v"(p0), "v"(p1));
                asm("v_cvt_pk_bf16_f32 %0, %1, %2" : "=v"(w1) : "v"(p2), "v"(p3));
                int k0 = j * 16 + lh * 4;
                int e = prow * 64 + (k0 ^ ((prow & 7) << 3));
                uint2 pk; pk.x = w0; pk.y = w1;
                *(uint2*)&Pw[e] = pk;
            }
        }

        // P frags + row-sums via ones-MFMA (lands in o-layout: no shuffles)
        bf16x8 ap[4][2];
        #pragma unroll
        for (int g = 0; g < 4; ++g) {
            int prow = g * 16 + lr;
            ap[g][0] = *(const bf16x8*)&Pw[prow * 64 + swz(prow,      lh * 8)];
            ap[g][1] = *(const bf16x8*)&Pw[prow * 64 + swz(prow, 32 + lh * 8)];
        }
        __builtin_amdgcn_s_setprio(1);
        #pragma unroll
        for (int g = 0; g < 4; ++g) {
            lacc[g] = __builtin_amdgcn_mfma_f32_16x16x32_bf16(ap[g][0], vone, lacc[g], 0, 0, 0);
            lacc[g] = __builtin_amdgcn_mfma_f32_16x16x32_bf16(ap[g][1], vone, lacc[g], 0, 0, 0);
        }
        // PV: V frags read ONCE, reused across 4 q-groups
        #pragma unroll
        for (int nf = 0; nf < 4; ++nf) {
            int vr = nf * 16 + lr;
            bf16x8 vb0 = *(const bf16x8*)&Vc[vr * 64 + swz(vr,      lh * 8)];
            bf16x8 vb1 = *(const bf16x8*)&Vc[vr * 64 + swz(vr, 32 + lh * 8)];
            #pragma unroll
            for (int g = 0; g < 4; ++g) {
                o[g][nf] = __builtin_amdgcn_mfma_f32_16x16x32_bf16(ap[g][0], vb0, o[g][nf], 0, 0, 0);
                o[g][nf] = __builtin_amdgcn_mfma_f32_16x16x32_bf16(ap[g][1], vb1, o[g][nf], 0, 0, 0);
            }
        }
        __builtin_amdgcn_s_setprio(0);

        __syncthreads();   // drains next-tile staging; all waves done with cur buffers
    }

    #pragma unroll
    for (int g = 0; g < 4; ++g) {
        float linv[4];
        #pragma unroll
        for (int r = 0; r < 4; ++r) linv[r] = frcp(lacc[g][r]);
        #pragma unroll
        for (int nf = 0; nf < 4; ++nf)
            #pragma unroll
            for (int r = 0; r < 4; ++r) {
                int row = qt * 256 + w * 64 + g * 16 + lh * 4 + r;   // seq pos
                ctx[((size_t)b * SEQ + row) * DM + h * 64 + nf * 16 + lr] =
                    f2bf(o[g][nf][r] * linv[r]);
            }
    }
}

extern "C" void kernel_launch(void* const* d_in, const int* in_sizes, int n_in,
                              void* d_out, int out_size, void* d_ws, size_t ws_size,
                              hipStream_t stream)
{
    const float* src   = (const float*)d_in[0];
    const float* qkv_w = (const float*)d_in[1];
    const float* qkv_b = (const float*)d_in[2];
    const float* out_w = (const float*)d_in[3];
    const float* out_b = (const float*)d_in[4];
    const float* ff1_w = (const float*)d_in[5];
    const float* ff1_b = (const float*)d_in[6];
    const float* ff2_w = (const float*)d_in[7];
    const float* ff2_b = (const float*)d_in[8];
    const float* n1_w  = (const float*)d_in[9];
    const float* n2_w  = (const float*)d_in[10];

    char* ws = (char*)d_ws;
    const size_t MB = 1u << 20;
    unsigned short* qkv_wt = (unsigned short*)(ws);            // 6 MB  [3072][1024]
    unsigned short* out_wt = (unsigned short*)(ws + 6*MB);     // 2 MB  [1024][1024]
    unsigned short* ff1_wt = (unsigned short*)(ws + 8*MB);     // 8 MB  [4096][1024]
    unsigned short* ff2_wt = (unsigned short*)(ws + 16*MB);    // 8 MB  [1024][4096]
    unsigned short* xb     = (unsigned short*)(ws + 24*MB);    // 16 MB
    unsigned short* qb     = (unsigned short*)(ws + 40*MB);    // 16 MB
    unsigned short* kb     = (unsigned short*)(ws + 56*MB);    // 16 MB
    unsigned short* vtb    = (unsigned short*)(ws + 72*MB);    // 16 MB
    unsigned short* hb     = (unsigned short*)(ws + 24*MB);    // 64 MB (overlays xb..vtb)
    unsigned short* ctxb   = (unsigned short*)(ws + 88*MB);    // 16 MB
    unsigned short* yb     = (unsigned short*)(ws + 88*MB);    // reuses ctx
    unsigned short* src2b  = (unsigned short*)(ws + 104*MB);   // 16 MB bf16 residual stream
    float* outp = (float*)d_out;

    // fused prep: 12288 transpose blocks + 8192 rmsnorm1 blocks
    prep_all<<<12288 + NTOK, 256, 0, stream>>>(qkv_w, out_w, ff1_w, ff2_w,
                                               qkv_wt, out_wt, ff1_wt, ff2_wt,
                                               src, n1_w, xb);

    // qkv: M=8192,N=3072 -> 256x256 tiles, 384 blocks; V-stores packed 8B
    gemm_tpl<0, 256><<<384, 512, 0, stream>>>(xb, qkv_wt, qkv_b, 3072, 1024, 12,
                                              nullptr, nullptr, nullptr, qb, kb, vtb);

    // attn: 512 blocks (8 XCD x 64), 256 q-rows per block, exactly 2/CU
    attn_kernel<<<SEQ/256 * BATCH*NH, 256, 0, stream>>>(qb, kb, vtb, ctxb);

    // out-proj: M=8192,N=1024 -> 256x128 tiles, 256 blocks (full chip, 1 round)
    gemm_tpl<4, 128><<<256, 512, 0, stream>>>(ctxb, out_wt, out_b, 1024, 1024, 8,
                                              src, nullptr, src2b, nullptr, nullptr, nullptr);

    rmsnorm_kernel<<<NTOK, 256, 0, stream>>>(src2b, n2_w, yb);

    // ff1: M=8192,N=4096 -> 256x256 tiles, 512 blocks (2 full rounds)
    gemm_tpl<2, 256><<<512, 512, 0, stream>>>(yb, ff1_wt, ff1_b, 4096, 1024, 16,
                                              nullptr, nullptr, hb, nullptr, nullptr, nullptr);

    // ff2: M=8192,N=1024,K=4096 -> m97-replica 128x128, 64x8 = 512 blocks (2 rounds, 3+/CU)
    gemm_ff2<<<512, 256, 0, stream>>>(hb, ff2_wt, ff2_b, 1024, 4096, 8, src2b, outp);
}

// Round 20
// 377.630 us; speedup vs baseline: 1.0307x; 1.0307x over previous
//
#include <hip/hip_runtime.h>
#include <hip/hip_bf16.h>

#define DM   1024
#define DFF  4096
#define NH   16
#define HD   64
#define SEQ  2048
#define BATCH 4
#define NTOK (BATCH*SEQ)

typedef float  f32x4  __attribute__((ext_vector_type(4)));
typedef short  bf16x8 __attribute__((ext_vector_type(8)));

#define SBAR() asm volatile("s_barrier" ::: "memory")
#define S_VMCNT(N) asm volatile("s_waitcnt vmcnt(" #N ")" ::: "memory")

__device__ __forceinline__ unsigned short f2bf(float f) {
    unsigned int x = __builtin_bit_cast(unsigned int, f);
    x += 0x7fff + ((x >> 16) & 1);          // RNE; inputs finite
    return (unsigned short)(x >> 16);
}
__device__ __forceinline__ float bf2f(unsigned short u) {
    unsigned int x = (unsigned int)u << 16;
    return __builtin_bit_cast(float, x);
}

__device__ __forceinline__ float fexp2(float x) {     // 2^x, single v_exp_f32
    float r; asm("v_exp_f32 %0, %1" : "=v"(r) : "v"(x)); return r;
}
__device__ __forceinline__ float frcp(float x) {
    float r; asm("v_rcp_f32 %0, %1" : "=v"(r) : "v"(x)); return r;
}

__device__ __forceinline__ void gload_lds16(const void* g, void* l) {
    // dest is wave-uniform base; HW writes base + lane*16
    __builtin_amdgcn_global_load_lds(
        (const __attribute__((address_space(1))) unsigned int*)g,
        (__attribute__((address_space(3))) unsigned int*)l,
        16, 0, 0);
}

// XOR swizzle for [R][64] bf16 tiles: element index within row
__device__ __forceinline__ int swz(int row, int elem) { return elem ^ ((row & 7) << 3); }

// ---------------- fused prep: weight transposes (blocks 0..12287) + rmsnorm1 (12288..) ----
__global__ __launch_bounds__(256)
void prep_all(const float* __restrict__ qkv_w, const float* __restrict__ out_w,
              const float* __restrict__ ff1_w, const float* __restrict__ ff2_w,
              unsigned short* __restrict__ qkv_wt, unsigned short* __restrict__ out_wt,
              unsigned short* __restrict__ ff1_wt, unsigned short* __restrict__ ff2_wt,
              const float* __restrict__ src, const float* __restrict__ n1_w,
              unsigned short* __restrict__ xb)
{
    __shared__ float tile[32][33];
    int b = blockIdx.x;
    if (b < 12288) {
        const float* W; unsigned short* Wt; int K, N, bx, by;
        if (b < 3072)      { W = qkv_w; Wt = qkv_wt; K = 1024; N = 3072; bx = b % 96;  by = b / 96;  }
        else if (b < 4096) { int i = b - 3072; W = out_w; Wt = out_wt; K = 1024; N = 1024; bx = i % 32;  by = i / 32; }
        else if (b < 8192) { int i = b - 4096; W = ff1_w; Wt = ff1_wt; K = 1024; N = 4096; bx = i % 128; by = i / 128; }
        else               { int i = b - 8192; W = ff2_w; Wt = ff2_wt; K = 4096; N = 1024; bx = i % 32;  by = i / 32; }
        int n0 = bx * 32, k0 = by * 32;
        int tx = threadIdx.x & 31, ty = threadIdx.x >> 5;   // 32 x 8
        #pragma unroll
        for (int i = 0; i < 4; ++i)
            tile[ty + i*8][tx] = W[(size_t)(k0 + ty + i*8) * N + n0 + tx];
        __syncthreads();
        #pragma unroll
        for (int i = 0; i < 4; ++i)
            Wt[(size_t)(n0 + ty + i*8) * K + k0 + tx] = f2bf(tile[tx][ty + i*8]);
    } else {
        int row = b - 12288, t = threadIdx.x;
        float4 v = ((const float4*)(src + (size_t)row * DM))[t];
        float ss = v.x*v.x + v.y*v.y + v.z*v.z + v.w*v.w;
        #pragma unroll
        for (int m = 1; m < 64; m <<= 1) ss += __shfl_xor(ss, m);
        if ((t & 63) == 0) tile[0][t >> 6] = ss;
        __syncthreads();
        float tot = tile[0][0] + tile[0][1] + tile[0][2] + tile[0][3];
        float rms = sqrtf(tot) * (1.f / 32.f);
        float inv = 1.f / (rms + 1e-8f);
        float4 wv = ((const float4*)n1_w)[t];
        unsigned int lo = (unsigned int)f2bf(v.x*inv*wv.x) | ((unsigned int)f2bf(v.y*inv*wv.y) << 16);
        unsigned int hi = (unsigned int)f2bf(v.z*inv*wv.z) | ((unsigned int)f2bf(v.w*inv*wv.w) << 16);
        uint2 pk; pk.x = lo; pk.y = hi;
        *(uint2*)(xb + (size_t)row * DM + t * 4) = pk;
    }
}

// ---------------- RMSNorm: bf16 in -> bf16 out (norm2) ----------------
__global__ __launch_bounds__(256)
void rmsnorm_kernel(const unsigned short* __restrict__ inp, const float* __restrict__ w,
                    unsigned short* __restrict__ out)
{
    __shared__ float red[4];
    int row = blockIdx.x, t = threadIdx.x;
    ushort4 u = ((const ushort4*)(inp + (size_t)row * DM))[t];
    float x0 = bf2f(u.x), x1 = bf2f(u.y), x2 = bf2f(u.z), x3 = bf2f(u.w);
    float ss = x0*x0 + x1*x1 + x2*x2 + x3*x3;
    #pragma unroll
    for (int m = 1; m < 64; m <<= 1) ss += __shfl_xor(ss, m);
    if ((t & 63) == 0) red[t >> 6] = ss;
    __syncthreads();
    float tot = red[0] + red[1] + red[2] + red[3];
    float rms = sqrtf(tot) * (1.f / 32.f);
    float inv = 1.f / (rms + 1e-8f);
    float4 wv = ((const float4*)w)[t];
    unsigned int lo = (unsigned int)f2bf(x0*inv*wv.x) | ((unsigned int)f2bf(x1*inv*wv.y) << 16);
    unsigned int hi = (unsigned int)f2bf(x2*inv*wv.z) | ((unsigned int)f2bf(x3*inv*wv.w) << 16);
    uint2 pk; pk.x = lo; pk.y = hi;
    *(uint2*)(out + (size_t)row * DM + t * 4) = pk;
}

// ---------------- 256xNB 8-phase GEMM, BK=64 as 2 K-halves, counted vmcnt (R14) ----------
// MODE 0: qkv scatter -> q (prescaled 0.125*log2e), k, v transposed (V packed 8B stores)
// MODE 2: out = gelu_tanh(acc + bias) (bf16)
// MODE 3: out = acc + bias + bf16resid (fp32 out)      [ff2]
// MODE 4: out = f2bf(acc + bias + fp32resid) (bf16 out) [out-proj]
template<int MODE, int NB>
__global__ __launch_bounds__(512, 2)
void gemm_tpl(const unsigned short* __restrict__ A,
              const unsigned short* __restrict__ Bt,
              const float* __restrict__ bias,
              int N, int K, int nx,
              const float* __restrict__ residf,
              const unsigned short* __restrict__ residb,
              float* __restrict__ outf,
              unsigned short* __restrict__ outb,
              unsigned short* __restrict__ q,
              unsigned short* __restrict__ kk,
              unsigned short* __restrict__ vt)
{
    constexpr int NJ = NB / 64;                        // B frags per wave
    constexpr int WN = NB / 4;                         // wave N extent
    __shared__ __align__(16) unsigned short Atile[2][2][256 * 32];
    __shared__ __align__(16) unsigned short Btile[2][2][NB * 32];
    const int tid = threadIdx.x, w = tid >> 6, l = tid & 63;
    const int lr = l & 15, lh = l >> 4;
    const int wm = w >> 2, wn = w & 3;                 // 2M x 4N
    const int nwg = gridDim.x, cpx = nwg >> 3;
    const int sid = (blockIdx.x & 7) * cpx + (blockIdx.x >> 3);
    const int by = sid / nx, bx = sid - by * nx;
    const int m0 = by * 256, n0 = bx * NB;
    const int nkt = K >> 6;
    // staging geometry: one gload covers 128 rows x 32 elems (8 waves x 16 rows)
    const int srow = w * 16 + (l >> 2);                // row within 128-row unit
    const int scol = (((l & 3) ^ (srow & 3)) << 3);    // pre-swizzled elem col

    auto stageA = [&](int kt, int ks, int half, int bi) {
        int r0 = half * 128;
        gload_lds16(A + (size_t)(m0 + r0 + srow) * K + kt * 64 + ks * 32 + scol,
                    &Atile[bi][ks][(r0 + w * 16) * 32]);
    };
    auto stageB = [&](int kt, int ks, int half, int bi) {
        int r0 = half * 128;
        gload_lds16(Bt + (size_t)(n0 + r0 + srow) * K + kt * 64 + ks * 32 + scol,
                    &Btile[bi][ks][(r0 + w * 16) * 32]);
    };

    f32x4 acc[8][NJ];
    #pragma unroll
    for (int a = 0; a < 8; ++a)
        #pragma unroll
        for (int j = 0; j < NJ; ++j) acc[a][j] = {0.f, 0.f, 0.f, 0.f};

    // prologue: tile 0, groups in wait-order [ks0][ks1]
    #pragma unroll
    for (int ks = 0; ks < 2; ++ks) {
        stageA(0, ks, 0, 0); stageA(0, ks, 1, 0);
        stageB(0, ks, 0, 0);
        if (NB == 256) stageB(0, ks, 1, 0);
    }

    int bi = 0;
    for (int t = 0; t < nkt; ++t) {
        #pragma unroll
        for (int ks = 0; ks < 2; ++ks) {
            // entry sync: this ks-half landed for all waves; one newer group may fly
            if (ks == 0 || t + 1 < nkt) {
                if constexpr (NB == 256) { S_VMCNT(4); } else { S_VMCNT(3); }
            } else {
                S_VMCNT(0);
            }
            SBAR();
            bf16x8 bB[NJ];
            #pragma unroll
            for (int j = 0; j < NJ; ++j) {
                int row = wn * WN + j * 16 + lr;
                bB[j] = *(const bf16x8*)&Btile[bi][ks][row * 32 + ((lh ^ (row & 3)) << 3)];
            }
            #pragma unroll
            for (int rho = 0; rho < 2; ++rho) {
                bf16x8 aA[4];
                #pragma unroll
                for (int i = 0; i < 4; ++i) {
                    int row = wm * 128 + rho * 64 + i * 16 + lr;
                    aA[i] = *(const bf16x8*)&Atile[bi][ks][row * 32 + ((lh ^ (row & 3)) << 3)];
                }
                // stage tile t+1: rho0 -> A-ks half, rho1 -> B-ks half
                if (t + 1 < nkt) {
                    if (rho == 0) { stageA(t + 1, ks, 0, bi ^ 1); stageA(t + 1, ks, 1, bi ^ 1); }
                    else          { stageB(t + 1, ks, 0, bi ^ 1);
                                    if (NB == 256) stageB(t + 1, ks, 1, bi ^ 1); }
                }
                SBAR();
                __builtin_amdgcn_s_setprio(1);
                #pragma unroll
                for (int i = 0; i < 4; ++i)
                    #pragma unroll
                    for (int j = 0; j < NJ; ++j)
                        acc[rho * 4 + i][j] = __builtin_amdgcn_mfma_f32_16x16x32_bf16(
                            aA[i], bB[j], acc[rho * 4 + i][j], 0, 0, 0);
                __builtin_amdgcn_s_setprio(0);
            }
        }
        bi ^= 1;
    }

    #pragma unroll
    for (int a = 0; a < 8; ++a) {
        const int rho = a >> 2, i = a & 3;
        #pragma unroll
        for (int j = 0; j < NJ; ++j) {
            const int col = n0 + wn * WN + j * 16 + lr;
            const int row0 = m0 + wm * 128 + rho * 64 + i * 16 + lh * 4;
            if (MODE == 0) {
                float v0 = acc[a][j][0] + bias[col];
                float v1 = acc[a][j][1] + bias[col];
                float v2 = acc[a][j][2] + bias[col];
                float v3 = acc[a][j][3] + bias[col];
                int wh = col >> 10, h = (col >> 6) & 15, d = col & 63;
                int b = row0 >> 11, s0 = row0 & 2047;
                size_t base = (size_t)(b * NH + h);
                if (wh == 0) {
                    q[(base * SEQ + s0    ) * HD + d] = f2bf(v0 * 0.18033688f);
                    q[(base * SEQ + s0 + 1) * HD + d] = f2bf(v1 * 0.18033688f);
                    q[(base * SEQ + s0 + 2) * HD + d] = f2bf(v2 * 0.18033688f);
                    q[(base * SEQ + s0 + 3) * HD + d] = f2bf(v3 * 0.18033688f);
                } else if (wh == 1) {
                    kk[(base * SEQ + s0    ) * HD + d] = f2bf(v0);
                    kk[(base * SEQ + s0 + 1) * HD + d] = f2bf(v1);
                    kk[(base * SEQ + s0 + 2) * HD + d] = f2bf(v2);
                    kk[(base * SEQ + s0 + 3) * HD + d] = f2bf(v3);
                } else {
                    // 4 consecutive s -> one 8B store into vt[d][s]
                    uint2 pk;
                    pk.x = (unsigned int)f2bf(v0) | ((unsigned int)f2bf(v1) << 16);
                    pk.y = (unsigned int)f2bf(v2) | ((unsigned int)f2bf(v3) << 16);
                    *(uint2*)&vt[(base * HD + d) * SEQ + s0] = pk;
                }
            } else {
                #pragma unroll
                for (int r = 0; r < 4; ++r) {
                    int row = row0 + r;
                    float v = acc[a][j][r] + bias[col];
                    if (MODE == 2) {
                        // tanh-form GELU: x*u/(u+1), u = 2^(2.3022079*(x+0.044715 x^3))
                        float x = v;
                        float t2 = fmaf(x * x * x, 0.044715f, x);
                        float av = fminf(t2 * 2.3022079f, 80.f);
                        float u = fexp2(av);
                        float g = x * u * frcp(u + 1.f);
                        outb[(size_t)row * N + col] = f2bf(g);
                    } else if (MODE == 3) {
                        outf[(size_t)row * N + col] = v + bf2f(residb[(size_t)row * N + col]);
                    } else {
                        outb[(size_t)row * N + col] = f2bf(v + residf[(size_t)row * N + col]);
                    }
                }
            }
        }
    }
}

// ---------------- flash attention: 4 waves x 64 q-rows (256/block), KVBLK=64 ----------------
// NO max-tracking (norm-bounded scores); row-sums via ones-column MFMA.
// 512 blocks @ 64KB = exactly 2/CU, no tail.
__global__ __launch_bounds__(256, 2)
void attn_kernel(const unsigned short* __restrict__ q,
                 const unsigned short* __restrict__ k,
                 const unsigned short* __restrict__ vt,
                 unsigned short* __restrict__ ctx)
{
    __shared__ __align__(16) unsigned short Ks[2][64 * 64];    // 16 KB
    __shared__ __align__(16) unsigned short Vs[2][64 * 64];    // 16 KB [d][s]
    __shared__ __align__(16) unsigned short PQ[4][64 * 64];    // 32 KB: Q prologue, then P

    const int tid = threadIdx.x, w = tid >> 6, l = tid & 63;
    const int lr = l & 15, lh = l >> 4;

    // XCD-chunked: 512 blocks = 8 XCDs x 64; each XCD owns 8 heads
    const int sid = (blockIdx.x & 7) * 64 + (blockIdx.x >> 3);
    const int bh = sid >> 3, qt = sid & 7;
    const int b = bh >> 4, h = bh & 15;

    const int rloc = l >> 3;
    const int cswz = (((l & 7) ^ rloc) << 3);

    const unsigned short* kbase0 = k  + (size_t)bh * SEQ * HD;
    const unsigned short* vbase0 = vt + (size_t)bh * HD * SEQ;
    const int NT = SEQ / 64;

    auto stageK = [&](int t, int buf) {
        const unsigned short* kb = kbase0 + (size_t)t * 64 * HD;
        #pragma unroll
        for (int c = 0; c < 2; ++c) {
            int r0 = (w * 2 + c) * 8;
            gload_lds16(kb + (size_t)(r0 + rloc) * HD + cswz, &Ks[buf][r0 * 64]);
        }
    };
    auto stageV = [&](int t, int buf) {
        const unsigned short* vb = vbase0 + t * 64;
        #pragma unroll
        for (int c = 0; c < 2; ++c) {
            int d0 = w * 16 + c * 8;
            gload_lds16(vb + (size_t)(d0 + rloc) * SEQ + cswz, &Vs[buf][d0 * 64]);
        }
    };

    // prologue: wave stages its OWN 64 Q rows into PQ[w], then K/V tile 0
    unsigned short* Pw = &PQ[w][0];
    const unsigned short* qbase = q + ((size_t)bh * SEQ + qt * 256 + w * 64) * HD;
    #pragma unroll
    for (int c = 0; c < 8; ++c) {
        int r0 = c * 8;
        gload_lds16(qbase + (size_t)(r0 + rloc) * HD + cswz, &Pw[r0 * 64]);
    }
    stageK(0, 0);
    stageV(0, 0);
    S_VMCNT(4);                                      // own 8 Q loads done (K/V are 4 newest)
    bf16x8 aq[4][2];
    #pragma unroll
    for (int g = 0; g < 4; ++g) {
        int row = g * 16 + lr;
        aq[g][0] = *(const bf16x8*)&Pw[row * 64 + swz(row,      lh * 8)];
        aq[g][1] = *(const bf16x8*)&Pw[row * 64 + swz(row, 32 + lh * 8)];
    }
    __syncthreads();                                 // K/V tile 0 visible; PQ free for P

    bf16x8 vone;
    #pragma unroll
    for (int i = 0; i < 8; ++i) vone[i] = (short)0x3F80;   // bf16 1.0

    f32x4 lacc[4];
    f32x4 o[4][4];
    #pragma unroll
    for (int g = 0; g < 4; ++g) {
        lacc[g] = {0.f, 0.f, 0.f, 0.f};
        #pragma unroll
        for (int nf = 0; nf < 4; ++nf) o[g][nf] = {0.f, 0.f, 0.f, 0.f};
    }

    for (int t = 0; t < NT; ++t) {
        const int cur = t & 1;
        if (t + 1 < NT) { stageK(t + 1, cur ^ 1); stageV(t + 1, cur ^ 1); }

        const unsigned short* Kc = &Ks[cur][0];
        const unsigned short* Vc = &Vs[cur][0];

        // K frags read ONCE, reused across 4 q-groups
        bf16x8 kb[4][2];
        #pragma unroll
        for (int j = 0; j < 4; ++j) {
            int kr = j * 16 + lr;
            kb[j][0] = *(const bf16x8*)&Kc[kr * 64 + swz(kr,      lh * 8)];
            kb[j][1] = *(const bf16x8*)&Kc[kr * 64 + swz(kr, 32 + lh * 8)];
        }

        #pragma unroll
        for (int g = 0; g < 4; ++g) {
            // QK^T (log2-scaled scores; lane owns q = g*16+lr)
            f32x4 sc[4];
            __builtin_amdgcn_s_setprio(1);
            #pragma unroll
            for (int j = 0; j < 4; ++j) {
                f32x4 z = {0.f, 0.f, 0.f, 0.f};
                z = __builtin_amdgcn_mfma_f32_16x16x32_bf16(kb[j][0], aq[g][0], z, 0, 0, 0);
                z = __builtin_amdgcn_mfma_f32_16x16x32_bf16(kb[j][1], aq[g][1], z, 0, 0, 0);
                sc[j] = z;
            }
            __builtin_amdgcn_s_setprio(0);

            // P = 2^s (no max subtraction needed), pack bf16, b64 store to swizzled Pw
            int prow = g * 16 + lr;
            #pragma unroll
            for (int j = 0; j < 4; ++j) {
                float p0 = fexp2(sc[j][0]), p1 = fexp2(sc[j][1]);
                float p2 = fexp2(sc[j][2]), p3 = fexp2(sc[j][3]);
                unsigned int w0, w1;
                asm("v_cvt_pk_bf16_f32 %0, %1, %2" : "=v"(w0) : "v"(p0), "v"(p1));
                asm("v_cvt_pk_bf16_f32 %0, %1, %2" : "=v"(w1) : "v"(p2), "v"(p3));
                int k0 = j * 16 + lh * 4;
                int e = prow * 64 + (k0 ^ ((prow & 7) << 3));
                uint2 pk; pk.x = w0; pk.y = w1;
                *(uint2*)&Pw[e] = pk;
            }
        }

        // P frags + row-sums via ones-MFMA (lands in o-layout: no shuffles)
        bf16x8 ap[4][2];
        #pragma unroll
        for (int g = 0; g < 4; ++g) {
            int prow = g * 16 + lr;
            ap[g][0] = *(const bf16x8*)&Pw[prow * 64 + swz(prow,      lh * 8)];
            ap[g][1] = *(const bf16x8*)&Pw[prow * 64 + swz(prow, 32 + lh * 8)];
        }
        __builtin_amdgcn_s_setprio(1);
        #pragma unroll
        for (int g = 0; g < 4; ++g) {
            lacc[g] = __builtin_amdgcn_mfma_f32_16x16x32_bf16(ap[g][0], vone, lacc[g], 0, 0, 0);
            lacc[g] = __builtin_amdgcn_mfma_f32_16x16x32_bf16(ap[g][1], vone, lacc[g], 0, 0, 0);
        }
        // PV: V frags read ONCE, reused across 4 q-groups
        #pragma unroll
        for (int nf = 0; nf < 4; ++nf) {
            int vr = nf * 16 + lr;
            bf16x8 vb0 = *(const bf16x8*)&Vc[vr * 64 + swz(vr,      lh * 8)];
            bf16x8 vb1 = *(const bf16x8*)&Vc[vr * 64 + swz(vr, 32 + lh * 8)];
            #pragma unroll
            for (int g = 0; g < 4; ++g) {
                o[g][nf] = __builtin_amdgcn_mfma_f32_16x16x32_bf16(ap[g][0], vb0, o[g][nf], 0, 0, 0);
                o[g][nf] = __builtin_amdgcn_mfma_f32_16x16x32_bf16(ap[g][1], vb1, o[g][nf], 0, 0, 0);
            }
        }
        __builtin_amdgcn_s_setprio(0);

        __syncthreads();   // drains next-tile staging; all waves done with cur buffers
    }

    #pragma unroll
    for (int g = 0; g < 4; ++g) {
        float linv[4];
        #pragma unroll
        for (int r = 0; r < 4; ++r) linv[r] = frcp(lacc[g][r]);
        #pragma unroll
        for (int nf = 0; nf < 4; ++nf)
            #pragma unroll
            for (int r = 0; r < 4; ++r) {
                int row = qt * 256 + w * 64 + g * 16 + lh * 4 + r;   // seq pos
                ctx[((size_t)b * SEQ + row) * DM + h * 64 + nf * 16 + lr] =
                    f2bf(o[g][nf][r] * linv[r]);
            }
    }
}

extern "C" void kernel_launch(void* const* d_in, const int* in_sizes, int n_in,
                              void* d_out, int out_size, void* d_ws, size_t ws_size,
                              hipStream_t stream)
{
    const float* src   = (const float*)d_in[0];
    const float* qkv_w = (const float*)d_in[1];
    const float* qkv_b = (const float*)d_in[2];
    const float* out_w = (const float*)d_in[3];
    const float* out_b = (const float*)d_in[4];
    const float* ff1_w = (const float*)d_in[5];
    const float* ff1_b = (const float*)d_in[6];
    const float* ff2_w = (const float*)d_in[7];
    const float* ff2_b = (const float*)d_in[8];
    const float* n1_w  = (const float*)d_in[9];
    const float* n2_w  = (const float*)d_in[10];

    char* ws = (char*)d_ws;
    const size_t MB = 1u << 20;
    unsigned short* qkv_wt = (unsigned short*)(ws);            // 6 MB  [3072][1024]
    unsigned short* out_wt = (unsigned short*)(ws + 6*MB);     // 2 MB  [1024][1024]
    unsigned short* ff1_wt = (unsigned short*)(ws + 8*MB);     // 8 MB  [4096][1024]
    unsigned short* ff2_wt = (unsigned short*)(ws + 16*MB);    // 8 MB  [1024][4096]
    unsigned short* xb     = (unsigned short*)(ws + 24*MB);    // 16 MB
    unsigned short* qb     = (unsigned short*)(ws + 40*MB);    // 16 MB
    unsigned short* kb     = (unsigned short*)(ws + 56*MB);    // 16 MB
    unsigned short* vtb    = (unsigned short*)(ws + 72*MB);    // 16 MB
    unsigned short* hb     = (unsigned short*)(ws + 24*MB);    // 64 MB (overlays xb..vtb)
    unsigned short* ctxb   = (unsigned short*)(ws + 88*MB);    // 16 MB
    unsigned short* yb     = (unsigned short*)(ws + 88*MB);    // reuses ctx
    unsigned short* src2b  = (unsigned short*)(ws + 104*MB);   // 16 MB bf16 residual stream
    float* outp = (float*)d_out;

    // fused prep: 12288 transpose blocks + 8192 rmsnorm1 blocks
    prep_all<<<12288 + NTOK, 256, 0, stream>>>(qkv_w, out_w, ff1_w, ff2_w,
                                               qkv_wt, out_wt, ff1_wt, ff2_wt,
                                               src, n1_w, xb);

    // qkv: M=8192,N=3072 -> 256x256 tiles, 384 blocks; V-stores packed 8B
    gemm_tpl<0, 256><<<384, 512, 0, stream>>>(xb, qkv_wt, qkv_b, 3072, 1024, 12,
                                              nullptr, nullptr, nullptr, nullptr, qb, kb, vtb);

    // attn: 512 blocks (8 XCD x 64), 256 q-rows per block, exactly 2/CU
    attn_kernel<<<SEQ/256 * BATCH*NH, 256, 0, stream>>>(qb, kb, vtb, ctxb);

    // out-proj: M=8192,N=1024 -> 256x128 tiles, 256 blocks (full chip, 1 round)
    gemm_tpl<4, 128><<<256, 512, 0, stream>>>(ctxb, out_wt, out_b, 1024, 1024, 8,
                                              src, nullptr, nullptr, src2b, nullptr, nullptr, nullptr);

    rmsnorm_kernel<<<NTOK, 256, 0, stream>>>(src2b, n2_w, yb);

    // ff1: M=8192,N=4096 -> 256x256 tiles, 512 blocks (2 full rounds)
    gemm_tpl<2, 256><<<512, 512, 0, stream>>>(yb, ff1_wt, ff1_b, 4096, 1024, 16,
                                              nullptr, nullptr, nullptr, hb, nullptr, nullptr, nullptr);

    // ff2: M=8192,N=1024,K=4096 -> 256x128 tiles, 256 blocks (full chip, 1 round)
    gemm_tpl<3, 128><<<256, 512, 0, stream>>>(hb, ff2_wt, ff2_b, 1024, 4096, 8,
                                              nullptr, src2b, outp, nullptr, nullptr, nullptr, nullptr);
}